// Round 7
// baseline (244.950 us; speedup 1.0000x reference)
//
#include <hip/hip_runtime.h>

// ---------------- constants ----------------
#define NS        4607          // series length: 512 + 4095
#define NTAIL     51            // tail blocks: 0 = GARCH, 1..50 = ACL lag k
#define RBLK      2048          // recon blocks
#define TPB       4             // tiles (256 px) per recon block
#define N_TOTAL   16777216.0    // 4096*512*8 elements in recon sum

// ws layout (floats):
#define WS_PART   0                     // [0, RBLK)  recon partials
#define WS_GARCH  RBLK                  // garch sum
#define WS_ACL    (RBLK + 1)            // 50 acl r^2 values
#define WS_SCR    (RBLK + 64)           // 51 private series buffers, stride 4672
#define SCR_STRIDE 4672

typedef float vf4 __attribute__((ext_vector_type(4)));

__device__ __forceinline__ float wave_sum(float v) {
    for (int o = 32; o > 0; o >>= 1) v += __shfl_down(v, o);
    return v;
}

// -------- Kernel 1: recon blocks (51..2098) + concurrent tail blocks (0..50) --------
// launch_bounds(256,4): VGPR cap 128 — 64 data + 16 addr + misc ≈ 98 fits.
__global__ __launch_bounds__(256, 4) void main_kernel(
    const float* __restrict__ x, const float* __restrict__ dec,
    float* __restrict__ ws)
{
    const int tid  = threadIdx.x;
    const int lane = tid & 63;
    const int wv   = tid >> 6;
    __shared__ float s4[4];

    if (blockIdx.x >= NTAIL) {
        // ========== recon: ALL-PLAIN cacheable loads, forced 16-deep pipeline ==========
        // EXPERIMENT (round 7): the last unrun cell {plain, genuinely-deep}.
        // Every prior plain measurement (r1/r2/r4: 91us, 1.15 TB/s HBM) ran with
        // COLLAPSED codegen (VGPR=36, ~5 in flight). This forces real depth via
        // volatile asm (cannot be collapsed/sunk), identical schedule to r5's
        // all-NT version (67.5us) — single variable: cache policy.
        // Upside mechanism: plain misses fetch full L2/L3 lines (vs NT 64B
        // sectors) AND ~100MB of the 201MB input is L3-resident across bench
        // iterations (r1/r2/r4 FETCH=100.8MB proves it); cache hits don't share
        // the ~3.1 TB/s HBM read ceiling (L2 uBench 34.5 TB/s).
        // If plain instead walls at ~2.2 TB/s payload: revert to r5, declare
        // read-roofline (r5 = 96% of the 3.1 TB/s read ceiling model).
        const int rb = blockIdx.x - NTAIL;
        float acc = 0.f;

        const long long pix0 = (long long)rb * (TPB * 256);
        const char* dbase = (const char*)dec + pix0 * 64;   // 64 B per pixel
        const char* xbase = (const char*)x   + pix0 * 32;   // 32 B per pixel
        const int  xi = ((tid >> 2) << 1) | (tid & 1);      // x idx (dup-pair)
        const bool im = (tid & 3) < 2;                      // q = tid&3

        // per-lane addresses, advanced by one tile (16KB / 8KB) after each burst
        const vf4* dp0 = (const vf4*)dbase + tid;
        const vf4* dp1 = dp0 + 256;
        const vf4* dp2 = dp0 + 512;
        const vf4* dp3 = dp0 + 768;
        const vf4* xp0 = (const vf4*)xbase + xi;
        const vf4* xp1 = xp0 + 128;
        const vf4* xp2 = xp0 + 256;
        const vf4* xp3 = xp0 + 384;

        vf4 dA0,dA1,dA2,dA3, xA0,xA1,xA2,xA3;   // buffer A (tiles 0,2)
        vf4 dB0,dB1,dB2,dB3, xB0,xB1,xB2,xB3;   // buffer B (tiles 1,3)

#define GL(dst, p) \
        asm volatile("global_load_dwordx4 %0, %1, off" : "=v"(dst) : "v"(p))

        // issue exactly 8 VMEM ops, then advance pointers one tile
#define LOADT(S) do { \
        GL(d##S##0, dp0); GL(x##S##0, xp0); \
        GL(d##S##1, dp1); GL(x##S##1, xp1); \
        GL(d##S##2, dp2); GL(x##S##2, xp2); \
        GL(d##S##3, dp3); GL(x##S##3, xp3); \
        dp0 += 1024; dp1 += 1024; dp2 += 1024; dp3 += 1024; \
        xp0 += 512;  xp1 += 512;  xp2 += 512;  xp3 += 512;  \
    } while (0)

#define WAITV(N) do { \
        asm volatile("s_waitcnt vmcnt(" #N ")" ::: "memory"); \
        __builtin_amdgcn_sched_barrier(0); \
    } while (0)

#define COMP(a, xx) do { \
        vf4 b; \
        b.x = __shfl_xor(a.x, 2); b.y = __shfl_xor(a.y, 2); \
        b.z = __shfl_xor(a.z, 2); b.w = __shfl_xor(a.w, 2); \
        float xe0 = im ? xx.x : xx.z; \
        float me0 = im ? a.x  : b.z;  \
        float le0 = im ? b.x  : a.z;  \
        float xe1 = im ? xx.y : xx.w; \
        float me1 = im ? a.y  : b.w;  \
        float le1 = im ? b.y  : a.w;  \
        float d0 = xe0 - me0, d1 = xe1 - me1; \
        acc += le0 + d0 * d0 * __expf(-le0); \
        acc += le1 + d1 * d1 * __expf(-le1); \
    } while (0)

        LOADT(A);                       // tile 0 in flight (8)
        LOADT(B);                       // tile 1 in flight (16)
        WAITV(8);                       // tile 0 landed
        COMP(dA0,xA0); COMP(dA1,xA1); COMP(dA2,xA2); COMP(dA3,xA3);
        LOADT(A);                       // tile 2 -> buffer A (16 in flight)
        WAITV(8);                       // tile 1 landed
        COMP(dB0,xB0); COMP(dB1,xB1); COMP(dB2,xB2); COMP(dB3,xB3);
        LOADT(B);                       // tile 3 -> buffer B (16 in flight)
        WAITV(8);                       // tile 2 landed
        COMP(dA0,xA0); COMP(dA1,xA1); COMP(dA2,xA2); COMP(dA3,xA3);
        WAITV(0);                       // tile 3 landed
        COMP(dB0,xB0); COMP(dB1,xB1); COMP(dB2,xB2); COMP(dB3,xB3);

#undef GL
#undef LOADT
#undef WAITV
#undef COMP

        acc = wave_sum(acc);
        if (lane == 0) s4[wv] = acc;
        __syncthreads();
        if (tid == 0) ws[WS_PART + rb] = s4[0] + s4[1] + s4[2] + s4[3];
    } else {
        // ============ tail block: private global scratch (no big LDS) ============
        const float OMEGA = 0.05f, ALPHA = 0.1f, BETA = 0.85f;
        float* scr = ws + WS_SCR + blockIdx.x * SCR_STRIDE;

        // gather series from dec (strided; hidden under recon), raw -> scratch
        float lsum = 0.f;
        for (int j = tid; j < NS; j += 256) {
            float v = (j < 512) ? dec[(long long)j * 16]
                                : dec[(long long)(j - 511) * 8192 + 8176];
            scr[j] = v;
            lsum += v;
        }
        lsum = wave_sum(lsum);
        __syncthreads();
        if (lane == 0) s4[wv] = lsum;
        __syncthreads();
        const float mean = (s4[0] + s4[1] + s4[2] + s4[3]) / (float)NS;

        // center in scratch + variance
        float vsum = 0.f;
        __syncthreads();
        for (int j = tid; j < NS; j += 256) {
            float v = scr[j] - mean;
            scr[j] = v;
            vsum += v * v;
        }
        vsum = wave_sum(vsum);
        __syncthreads();
        if (lane == 0) s4[wv] = vsum;
        __syncthreads();
        const float var = s4[0] + s4[1] + s4[2] + s4[3];

        if (blockIdx.x == 0) {
            // ---- GARCH: chunked scan, shfl compose (segment: x_out = p*x_in + e) ----
            const int start = tid * 18;
            const int end   = min(start + 18, NS);
            float e = 0.f, p = 1.f;
            for (int i = start; i < end; ++i) {
                float r2 = scr[i] * scr[i];
                e = (OMEGA + ALPHA * r2) + BETA * e;
                p *= BETA;
            }
            for (int o = 1; o < 64; o <<= 1) {          // wave inclusive scan
                float pe = __shfl_up(e, o), pp = __shfl_up(p, o);
                if (lane >= o) { e = e + p * pe; p = p * pp; }
            }
            __shared__ float wE[4], wP[4];
            if (lane == 63) { wE[wv] = e; wP[wv] = p; }
            __syncthreads();
            float cE = 0.f, cP = 1.f;
            for (int t = 0; t < wv; ++t) { cE = wE[t] + wP[t] * cE; cP = wP[t] * cP; }
            float eE = __shfl_up(e, 1), eP = __shfl_up(p, 1);
            if (lane == 0) { eE = 0.f; eP = 1.f; }
            float prev = (eE + eP * cE) + (eP * cP) * 1.0f;   // sigma0 = 1.0
            float g = 0.f;
            for (int i = start; i < end; ++i) {
                float r2 = scr[i] * scr[i];
                float cv = OMEGA + ALPHA * r2 + BETA * prev;
                prev = cv;
                g += 0.5f * logf(0.5f * cv) + 2.5f * log1pf(r2 / (2.f * cv));
            }
            g = wave_sum(g);
            __syncthreads();
            if (lane == 0) s4[wv] = g;
            __syncthreads();
            if (tid == 0) ws[WS_GARCH] = s4[0] + s4[1] + s4[2] + s4[3];
        } else {
            // ---- ACL lag k ----
            const int k = blockIdx.x;   // 1..50
            float a = 0.f;
            for (int i = tid; i < NS - k; i += 256) a += scr[i] * scr[i + k];
            a = wave_sum(a);
            __syncthreads();
            if (lane == 0) s4[wv] = a;
            __syncthreads();
            if (tid == 0) {
                float r = (s4[0] + s4[1] + s4[2] + s4[3]) / var;
                ws[WS_ACL + (k - 1)] = r * r;
            }
        }
    }
}

// -------- Kernel 2: final combine (dispatch boundary provides coherence) --------
__global__ __launch_bounds__(256) void final_kernel(
    const float* __restrict__ ws, float* __restrict__ out)
{
    const int tid  = threadIdx.x;
    const int lane = tid & 63;
    const int wv   = tid >> 6;
    __shared__ double d4[4];
    __shared__ float  aclbuf[1];

    double ds = 0.0;
    for (int i = tid; i < RBLK; i += 256) ds += (double)ws[WS_PART + i];
    for (int o = 32; o > 0; o >>= 1) ds += __shfl_down(ds, o);
    if (lane == 0) d4[wv] = ds;

    if (wv == 0) {
        float av = (lane < 50) ? ws[WS_ACL + lane] : 0.f;
        av = wave_sum(av);
        if (lane == 0) aclbuf[0] = av;
    }
    __syncthreads();

    if (tid == 0) {
        const double LOG_2PI = 1.8378770664093453;
        const double NEG_C   = 0.9808292530117262; // -(gammaln(2.5)-gammaln(2)-0.5*log(4*pi))
        double q = d4[0] + d4[1] + d4[2] + d4[3];
        double recon = 0.5 * (q + N_TOTAL * LOG_2PI) / 4096.0;
        double acl   = (double)aclbuf[0] / 50.0;
        double garch = (double)ws[WS_GARCH] + (double)NS * NEG_C;
        out[0] = (float)(recon + 10.0 * acl + 0.001 * garch);
    }
}

extern "C" void kernel_launch(void* const* d_in, const int* in_sizes, int n_in,
                              void* d_out, int out_size, void* d_ws, size_t ws_size,
                              hipStream_t stream) {
    const float* x_true  = (const float*)d_in[0];   // 4096*512*8
    const float* dec_out = (const float*)d_in[1];   // 4096*512*16
    float* ws  = (float*)d_ws;
    float* out = (float*)d_out;

    main_kernel<<<RBLK + NTAIL, 256, 0, stream>>>(x_true, dec_out, ws);
    final_kernel<<<1, 256, 0, stream>>>(ws, out);
}

// Round 8
// 229.252 us; speedup vs baseline: 1.0685x; 1.0685x over previous
//
#include <hip/hip_runtime.h>

// ---------------- constants ----------------
#define NS        4607          // series length: 512 + 4095
#define NTAIL     51            // tail blocks: 0 = GARCH, 1..50 = ACL lag k
#define RBLK      2048          // recon blocks
#define TPB       4             // tiles (256 px) per recon block
#define N_TOTAL   16777216.0    // 4096*512*8 elements in recon sum

// ws layout (floats):
#define WS_PART   0                     // [0, RBLK)  recon partials
#define WS_GARCH  RBLK                  // garch sum
#define WS_ACL    (RBLK + 1)            // 50 acl r^2 values
#define WS_SCR    (RBLK + 64)           // 51 private series buffers, stride 4672
#define SCR_STRIDE 4672

typedef float vf4 __attribute__((ext_vector_type(4)));

__device__ __forceinline__ float wave_sum(float v) {
    for (int o = 32; o > 0; o >>= 1) v += __shfl_down(v, o);
    return v;
}

// -------- Kernel 1: recon blocks (51..2098) + concurrent tail blocks (0..50) --------
// launch_bounds(256,4): VGPR cap 128.
// FINAL CONFIG (session grid complete):
//   NT collapsed=72us | NT forced-16-deep=67.5us (THIS) | plain any depth=91-94us
//   | mixed NT+plain=74us (vmcnt head-of-line blocking).
// Model: gfx950 read fabric ceiling ~3.1 TB/s (copy uBench 6.29 total at 1:1);
// NT streams 201MB at 2.98 TB/s = 96% of read ceiling. Plain pays an
// allocate/probe penalty (~2.2 TB/s wall, depth-independent, r7).
__global__ __launch_bounds__(256, 4) void main_kernel(
    const float* __restrict__ x, const float* __restrict__ dec,
    float* __restrict__ ws)
{
    const int tid  = threadIdx.x;
    const int lane = tid & 63;
    const int wv   = tid >> 6;
    __shared__ float s4[4];

    if (blockIdx.x >= NTAIL) {
        // ============ recon: inline-asm NT burst, counted-vmcnt pipeline ============
        // Volatile inline-asm global_load_dwordx4 nt (compiler cannot collapse,
        // sink, or split — r1/r2/r4 proved C-level bursts always collapse to
        // VGPR=36/~5-deep). 2-tile rotating register buffer: 16 loads in flight,
        // drain 8 / refill 8 per tile via explicit s_waitcnt vmcnt(8).
        // sched_barrier(0) after each waitcnt is MANDATORY (rule #18): the
        // compiler does not track vmcnt for asm-produced values and would
        // otherwise hoist reads of the load destinations above the wait.
        const int rb = blockIdx.x - NTAIL;
        float acc = 0.f;

        const long long pix0 = (long long)rb * (TPB * 256);
        const char* dbase = (const char*)dec + pix0 * 64;   // 64 B per pixel
        const char* xbase = (const char*)x   + pix0 * 32;   // 32 B per pixel
        const int  xi = ((tid >> 2) << 1) | (tid & 1);      // x idx (dup-pair)
        const bool im = (tid & 3) < 2;                      // q = tid&3

        // per-lane addresses, advanced by one tile (16KB / 8KB) after each burst
        const vf4* dp0 = (const vf4*)dbase + tid;
        const vf4* dp1 = dp0 + 256;
        const vf4* dp2 = dp0 + 512;
        const vf4* dp3 = dp0 + 768;
        const vf4* xp0 = (const vf4*)xbase + xi;
        const vf4* xp1 = xp0 + 128;
        const vf4* xp2 = xp0 + 256;
        const vf4* xp3 = xp0 + 384;

        vf4 dA0,dA1,dA2,dA3, xA0,xA1,xA2,xA3;   // buffer A (tiles 0,2)
        vf4 dB0,dB1,dB2,dB3, xB0,xB1,xB2,xB3;   // buffer B (tiles 1,3)

#define GL(dst, p) \
        asm volatile("global_load_dwordx4 %0, %1, off nt" : "=v"(dst) : "v"(p))

        // issue exactly 8 VMEM ops, then advance pointers one tile
#define LOADT(S) do { \
        GL(d##S##0, dp0); GL(x##S##0, xp0); \
        GL(d##S##1, dp1); GL(x##S##1, xp1); \
        GL(d##S##2, dp2); GL(x##S##2, xp2); \
        GL(d##S##3, dp3); GL(x##S##3, xp3); \
        dp0 += 1024; dp1 += 1024; dp2 += 1024; dp3 += 1024; \
        xp0 += 512;  xp1 += 512;  xp2 += 512;  xp3 += 512;  \
    } while (0)

#define WAITV(N) do { \
        asm volatile("s_waitcnt vmcnt(" #N ")" ::: "memory"); \
        __builtin_amdgcn_sched_barrier(0); \
    } while (0)

#define COMP(a, xx) do { \
        vf4 b; \
        b.x = __shfl_xor(a.x, 2); b.y = __shfl_xor(a.y, 2); \
        b.z = __shfl_xor(a.z, 2); b.w = __shfl_xor(a.w, 2); \
        float xe0 = im ? xx.x : xx.z; \
        float me0 = im ? a.x  : b.z;  \
        float le0 = im ? b.x  : a.z;  \
        float xe1 = im ? xx.y : xx.w; \
        float me1 = im ? a.y  : b.w;  \
        float le1 = im ? b.y  : a.w;  \
        float d0 = xe0 - me0, d1 = xe1 - me1; \
        acc += le0 + d0 * d0 * __expf(-le0); \
        acc += le1 + d1 * d1 * __expf(-le1); \
    } while (0)

        LOADT(A);                       // tile 0 in flight (8)
        LOADT(B);                       // tile 1 in flight (16)
        WAITV(8);                       // tile 0 landed
        COMP(dA0,xA0); COMP(dA1,xA1); COMP(dA2,xA2); COMP(dA3,xA3);
        LOADT(A);                       // tile 2 -> buffer A (16 in flight)
        WAITV(8);                       // tile 1 landed
        COMP(dB0,xB0); COMP(dB1,xB1); COMP(dB2,xB2); COMP(dB3,xB3);
        LOADT(B);                       // tile 3 -> buffer B (16 in flight)
        WAITV(8);                       // tile 2 landed
        COMP(dA0,xA0); COMP(dA1,xA1); COMP(dA2,xA2); COMP(dA3,xA3);
        WAITV(0);                       // tile 3 landed
        COMP(dB0,xB0); COMP(dB1,xB1); COMP(dB2,xB2); COMP(dB3,xB3);

#undef GL
#undef LOADT
#undef WAITV
#undef COMP

        acc = wave_sum(acc);
        if (lane == 0) s4[wv] = acc;
        __syncthreads();
        if (tid == 0) ws[WS_PART + rb] = s4[0] + s4[1] + s4[2] + s4[3];
    } else {
        // ============ tail block: private global scratch (no big LDS) ============
        const float OMEGA = 0.05f, ALPHA = 0.1f, BETA = 0.85f;
        float* scr = ws + WS_SCR + blockIdx.x * SCR_STRIDE;

        // gather series from dec (strided; hidden under recon), raw -> scratch
        float lsum = 0.f;
        for (int j = tid; j < NS; j += 256) {
            float v = (j < 512) ? dec[(long long)j * 16]
                                : dec[(long long)(j - 511) * 8192 + 8176];
            scr[j] = v;
            lsum += v;
        }
        lsum = wave_sum(lsum);
        __syncthreads();
        if (lane == 0) s4[wv] = lsum;
        __syncthreads();
        const float mean = (s4[0] + s4[1] + s4[2] + s4[3]) / (float)NS;

        // center in scratch + variance
        float vsum = 0.f;
        __syncthreads();
        for (int j = tid; j < NS; j += 256) {
            float v = scr[j] - mean;
            scr[j] = v;
            vsum += v * v;
        }
        vsum = wave_sum(vsum);
        __syncthreads();
        if (lane == 0) s4[wv] = vsum;
        __syncthreads();
        const float var = s4[0] + s4[1] + s4[2] + s4[3];

        if (blockIdx.x == 0) {
            // ---- GARCH: chunked scan, shfl compose (segment: x_out = p*x_in + e) ----
            const int start = tid * 18;
            const int end   = min(start + 18, NS);
            float e = 0.f, p = 1.f;
            for (int i = start; i < end; ++i) {
                float r2 = scr[i] * scr[i];
                e = (OMEGA + ALPHA * r2) + BETA * e;
                p *= BETA;
            }
            for (int o = 1; o < 64; o <<= 1) {          // wave inclusive scan
                float pe = __shfl_up(e, o), pp = __shfl_up(p, o);
                if (lane >= o) { e = e + p * pe; p = p * pp; }
            }
            __shared__ float wE[4], wP[4];
            if (lane == 63) { wE[wv] = e; wP[wv] = p; }
            __syncthreads();
            float cE = 0.f, cP = 1.f;
            for (int t = 0; t < wv; ++t) { cE = wE[t] + wP[t] * cE; cP = wP[t] * cP; }
            float eE = __shfl_up(e, 1), eP = __shfl_up(p, 1);
            if (lane == 0) { eE = 0.f; eP = 1.f; }
            float prev = (eE + eP * cE) + (eP * cP) * 1.0f;   // sigma0 = 1.0
            float g = 0.f;
            for (int i = start; i < end; ++i) {
                float r2 = scr[i] * scr[i];
                float cv = OMEGA + ALPHA * r2 + BETA * prev;
                prev = cv;
                g += 0.5f * logf(0.5f * cv) + 2.5f * log1pf(r2 / (2.f * cv));
            }
            g = wave_sum(g);
            __syncthreads();
            if (lane == 0) s4[wv] = g;
            __syncthreads();
            if (tid == 0) ws[WS_GARCH] = s4[0] + s4[1] + s4[2] + s4[3];
        } else {
            // ---- ACL lag k ----
            const int k = blockIdx.x;   // 1..50
            float a = 0.f;
            for (int i = tid; i < NS - k; i += 256) a += scr[i] * scr[i + k];
            a = wave_sum(a);
            __syncthreads();
            if (lane == 0) s4[wv] = a;
            __syncthreads();
            if (tid == 0) {
                float r = (s4[0] + s4[1] + s4[2] + s4[3]) / var;
                ws[WS_ACL + (k - 1)] = r * r;
            }
        }
    }
}

// -------- Kernel 2: final combine (dispatch boundary provides coherence) --------
__global__ __launch_bounds__(256) void final_kernel(
    const float* __restrict__ ws, float* __restrict__ out)
{
    const int tid  = threadIdx.x;
    const int lane = tid & 63;
    const int wv   = tid >> 6;
    __shared__ double d4[4];
    __shared__ float  aclbuf[1];

    double ds = 0.0;
    for (int i = tid; i < RBLK; i += 256) ds += (double)ws[WS_PART + i];
    for (int o = 32; o > 0; o >>= 1) ds += __shfl_down(ds, o);
    if (lane == 0) d4[wv] = ds;

    if (wv == 0) {
        float av = (lane < 50) ? ws[WS_ACL + lane] : 0.f;
        av = wave_sum(av);
        if (lane == 0) aclbuf[0] = av;
    }
    __syncthreads();

    if (tid == 0) {
        const double LOG_2PI = 1.8378770664093453;
        const double NEG_C   = 0.9808292530117262; // -(gammaln(2.5)-gammaln(2)-0.5*log(4*pi))
        double q = d4[0] + d4[1] + d4[2] + d4[3];
        double recon = 0.5 * (q + N_TOTAL * LOG_2PI) / 4096.0;
        double acl   = (double)aclbuf[0] / 50.0;
        double garch = (double)ws[WS_GARCH] + (double)NS * NEG_C;
        out[0] = (float)(recon + 10.0 * acl + 0.001 * garch);
    }
}

extern "C" void kernel_launch(void* const* d_in, const int* in_sizes, int n_in,
                              void* d_out, int out_size, void* d_ws, size_t ws_size,
                              hipStream_t stream) {
    const float* x_true  = (const float*)d_in[0];   // 4096*512*8
    const float* dec_out = (const float*)d_in[1];   // 4096*512*16
    float* ws  = (float*)d_ws;
    float* out = (float*)d_out;

    main_kernel<<<RBLK + NTAIL, 256, 0, stream>>>(x_true, dec_out, ws);
    final_kernel<<<1, 256, 0, stream>>>(ws, out);
}